// Round 7
// baseline (243.132 us; speedup 1.0000x reference)
//
#include <hip/hip_runtime.h>

#define MAXB 64
#define CAP 256

__constant__ float c_anc[9][2] = {
    {116.f, 90.f}, {156.f, 198.f}, {373.f, 326.f},
    { 30.f, 61.f}, { 62.f, 45.f}, { 59.f, 119.f},
    { 10.f, 13.f}, { 16.f, 30.f}, { 33.f, 23.f}};

typedef float floatx4 __attribute__((ext_vector_type(4), aligned(4)));

// fast transcendentals (v_exp/v_log/v_rcp); ~1e-6 rel per term, output ~1.7e4
// with threshold 345.6 -> ample margin.
__device__ __forceinline__ float sigm(float x) {
    return __builtin_amdgcn_rcpf(1.f + __expf(-x));
}
// bce_logits(t,x) = max(x,0) - x*t + log1p(exp(-|x|))
__device__ __forceinline__ float bce_f(float t, float x) {
    return fmaxf(x, 0.f) - x * t + __logf(1.f + __expf(-fabsf(x)));
}

__global__ void init_k(float* __restrict__ out) { out[threadIdx.x] = 0.f; }

struct SmemT {
    unsigned long long swords[128];
    int sidx[CAP];
    int sbase2[2];
    int stot_s;
    float sxmin[MAXB], sxmax[MAXB], symin[MAXB], symax[MAXB], sba[MAXB];
    float wred[16];
};

// One (batch,layer) pair handled by 1 block (L=0,1) or 2 half-blocks (L=2).
// Self-contained: each block derives the pair's positive set from y_true in
// LDS (no workspace round-trip -> nothing for the 0xAA poison to corrupt).
// SC = scan words/wave-pass, PR = processed cells/thread.
template <int SC, int PR, int L>
__device__ __forceinline__ void pair_body(
    int b, int half, const float* __restrict__ yt,
    const float* __restrict__ pred, float* __restrict__ out,
    SmemT& sm, int tid, int lane, int wv)
{
    constexpr int S      = (L == 0) ? 13 : (L == 1) ? 26  : 52;
    constexpr int n0     = (L == 0) ? 0  : (L == 1) ? 169 : 845;
    constexpr int nwords = (L == 0) ? 8  : (L == 1) ? 32  : 128;
    constexpr int nCells = S * S * 3;
    constexpr int halfSz = (L == 2) ? 4056 : nCells;
    const float Sf = (float)S;
    const float invS = 1.f / Sf;
    const float* ybase = yt + (long long)(b * 3549 + n0) * 255;
    const float* pbase = pred + (long long)b * S * S * 255;

    // ---- 1) issue ALL obj-scan loads (needed first: oldest in vmcnt order) --
    float ov[SC];
#pragma unroll
    for (int k = 0; k < SC; ++k) {
        int wi = k * 16 + wv;
        int c = (wi << 6) + lane;
        ov[k] = (wi < nwords && c < nCells) ? ybase[(long long)c * 85] : 0.f;
    }

    // ---- 2) issue ALL pred loads for this block's cells (stay in flight) ---
    int start = half * halfSz;
    bool act[PR]; int cc[PR]; floatx4 v03[PR]; float v4[PR];
#pragma unroll
    for (int i = 0; i < PR; ++i) {
        int c = start + tid + i * 1024;
        bool a = (tid + i * 1024 < halfSz) && (c < nCells);
        act[i] = a; cc[i] = a ? c : 0;
        const float* pp = pbase + (long long)cc[i] * 85;
        v03[i] = *(const floatx4*)pp;
        v4[i]  = pp[4];
    }

    // ---- 3) ballots -> LDS bitmap (waits only on obj loads) ----------------
#pragma unroll
    for (int k = 0; k < SC; ++k) {
        int wi = k * 16 + wv;
        unsigned long long m = __ballot(ov[k] > 0.5f);
        if (lane == 0 && wi < nwords) sm.swords[wi] = m;
    }
    __syncthreads();

    // ---- 4) exclusive prefix over word popcounts (waves 0/1) ---------------
    unsigned long long w = 0ULL;
    int pc = 0;
    if (tid < 128) { w = (tid < nwords) ? sm.swords[tid] : 0ULL; pc = __popcll(w); }
    int x = pc;
#pragma unroll
    for (int d = 1; d < 64; d <<= 1) {
        int y = __shfl_up(x, d, 64);
        if (lane >= d) x += y;
    }
    if (tid < 128 && lane == 63) sm.sbase2[wv] = x;
    __syncthreads();
    if (tid == 0) sm.stot_s = sm.sbase2[0] + sm.sbase2[1];
    if (tid < 128) {
        int base = x - pc + (wv ? sm.sbase2[0] : 0);
        unsigned long long ww = w;
        while (ww) {
            int bit = __ffsll((long long)ww) - 1;
            if (base < CAP) sm.sidx[base] = tid * 64 + bit;
            ++base;
            ww &= ww - 1;
        }
    }
    __syncthreads();

    int stot = sm.stot_s;
    int TC = stot < CAP ? stot : CAP;
    int MB = TC < MAXB ? TC : MAXB;   // == top_k(64) box set (index-ordered)
    if (tid < MB) {
        int idx = sm.sidx[tid];
        if (idx >= nCells) idx = nCells - 1;          // defensive clamp
        const float* yc = ybase + (long long)idx * 85;
        floatx4 g = *(const floatx4*)(yc + 1);        // [x,y,w,h]
        sm.sxmin[tid] = g.x - g.z * 0.5f; sm.sxmax[tid] = g.x + g.z * 0.5f;
        sm.symin[tid] = g.y - g.w * 0.5f; sm.symax[tid] = g.y + g.w * 0.5f;
        sm.sba[tid]   = g.z * g.w;
    }
    __syncthreads();

    // ---- 5) negative-conf losses for this block's cells (branchless) -------
    float loss = 0.f;
#pragma unroll
    for (int i = 0; i < PR; ++i) {
        int c = cc[i];
        int p_ = c / 3, a = c - p_ * 3;
        int gh = p_ / S, gw = p_ - gh * S;
        float aw = c_anc[L * 3 + a][0], ah = c_anc[L * 3 + a][1];
        float px = (sigm(v03[i].y) + (float)gw) * invS;
        float py = (sigm(v03[i].z) + (float)gh) * invS;
        float pw = __expf(v03[i].w) * aw * invS, ph = __expf(v4[i]) * ah * invS;
        float pxmin = px - pw * 0.5f, pxmax = px + pw * 0.5f;
        float pymin = py - ph * 0.5f, pymax = py + ph * 0.5f;
        float parea = pw * ph;
        bool hit = false;
        // iou >= 0.5  <=>  2*inter >= pa+ba-inter  <=>  3*inter >= pa+ba
        for (int k = 0; k < MB; ++k) {
            float iw = fminf(pxmax, sm.sxmax[k]) - fmaxf(pxmin, sm.sxmin[k]);
            float ih = fminf(pymax, sm.symax[k]) - fmaxf(pymin, sm.symin[k]);
            float inter = fmaxf(iw, 0.f) * fmaxf(ih, 0.f);
            hit = hit || (3.f * inter >= parea + sm.sba[k]);
        }
        bool posbit = (sm.swords[c >> 6] >> (c & 63)) & 1ULL;
        float conf = sigm(v03[i].x);
        float bval = fmaxf(conf, 0.f) + __logf(1.f + __expf(-fabsf(conf)));
        loss += (act[i] && !posbit && !hit) ? bval : 0.f;
    }

    // ---- 6) positive losses (one block per pair: half==0) ------------------
    if (half == 0) {
        float wsum = 0.f;
        for (int i = wv; i < TC; i += 16) {
            int idx = sm.sidx[i];
            if (idx >= nCells) idx = nCells - 1;      // defensive clamp
            const float* yc = ybase + (long long)idx * 85;
            const float* pp = pbase + (long long)idx * 85;
            float part = bce_f(yc[5 + lane], sigm(pp[5 + lane]));
            if (lane < 16)
                part += bce_f(yc[69 + lane], sigm(pp[69 + lane]));
            if (lane == 0) {
                int q = idx / 3, aa = idx - q * 3;
                int qh = q / S, qw = q - qh * S;
                float aw2 = c_anc[L * 3 + aa][0], ah2 = c_anc[L * 3 + aa][1];
                float t1 = yc[1], t2 = yc[2], t3 = yc[3], t4 = yc[4];
                float u0 = pp[0], u1 = pp[1], u2 = pp[2], u3 = pp[3], u4 = pp[4];
                part += bce_f(1.f, sigm(u0));
                float sc = 2.f - t3 * t4;
                float qx = (sigm(u1) + (float)qw) * invS;
                float qy = (sigm(u2) + (float)qh) * invS;
                part += sc * (bce_f(t1 * Sf - (float)qw, qx) +
                              bce_f(t2 * Sf - (float)qh, qy));
                float qpw = __expf(u3) * aw2 * invS;
                float qph = __expf(u4) * ah2 * invS;
                float twx = __logf(t3 / aw2 * 416.f);
                float twy = __logf(t4 / ah2 * 416.f);
                part += sc * 0.5f *
                        ((twx - qpw) * (twx - qpw) + (twy - qph) * (twy - qph));
            }
#pragma unroll
            for (int off = 32; off > 0; off >>= 1)
                part += __shfl_down(part, off, 64);
            if (lane == 0) wsum += part;
        }
        if (lane == 0) loss += wsum;
    }

    // ---- 7) block reduction -> one atomicAdd per block ---------------------
#pragma unroll
    for (int off = 32; off > 0; off >>= 1)
        loss += __shfl_down(loss, off, 64);
    if (lane == 0) sm.wred[wv] = loss;
    __syncthreads();
    if (tid == 0) {
        float s = 0.f;
#pragma unroll
        for (int k = 0; k < 16; ++k) s += sm.wred[k];
        atomicAdd(out + b, s);
    }
}

// 128 blocks x 1024 threads: per batch j=0 -> 13x13, j=1 -> 26x26,
// j=2/3 -> 52x52 half A/B (each scans full column, processes half).
__global__ __launch_bounds__(1024) void loss_k(
    const float* __restrict__ yt,
    const float* __restrict__ p13, const float* __restrict__ p26,
    const float* __restrict__ p52, float* __restrict__ out)
{
    __shared__ SmemT sm;
    int bid = blockIdx.x, tid = threadIdx.x;
    int b = bid >> 2, j = bid & 3;
    int lane = tid & 63, wv = tid >> 6;
    if (j == 0)
        pair_body<1, 1, 0>(b, 0, yt, p13, out, sm, tid, lane, wv);
    else if (j == 1)
        pair_body<2, 2, 1>(b, 0, yt, p26, out, sm, tid, lane, wv);
    else
        pair_body<8, 4, 2>(b, j - 2, yt, p52, out, sm, tid, lane, wv);
}

extern "C" void kernel_launch(void* const* d_in, const int* in_sizes, int n_in,
                              void* d_out, int out_size, void* d_ws, size_t ws_size,
                              hipStream_t stream) {
    (void)in_sizes; (void)n_in; (void)out_size; (void)d_ws; (void)ws_size;
    const float* yt  = (const float*)d_in[0];
    const float* p13 = (const float*)d_in[1];
    const float* p26 = (const float*)d_in[2];
    const float* p52 = (const float*)d_in[3];
    float* out = (float*)d_out;

    init_k<<<1, 32, 0, stream>>>(out);
    loss_k<<<32 * 4, 1024, 0, stream>>>(yt, p13, p26, p52, out);
}